// Round 9
// baseline (190.772 us; speedup 1.0000x reference)
//
#include <hip/hip_runtime.h>
#include <math.h>

#define NB 4
#define LQ 512
#define LK 512
#define DM 512
#define NH 8
#define DQ 64
#define NL 8
#define QT 32          // q-rows per attn block
#define PSTR 520       // Ps row stride in shorts (520*2B=1040B, 260dw%32=4 -> <=2-way)

typedef short bf16x8 __attribute__((ext_vector_type(8)));
typedef float f32x4 __attribute__((ext_vector_type(4)));

__device__ __forceinline__ unsigned short f2bf(float x) {
    unsigned u = __float_as_uint(x);
    u += 0x7fff + ((u >> 16) & 1);          // RNE
    return (unsigned short)(u >> 16);
}
__device__ __forceinline__ float bf2f(unsigned x) {
    return __uint_as_float(x << 16);
}

// ---------------------------------------------------------------------------
// prep: fp32->bf16 conversion of q,k,w_q,w_k,w_v,w_h (y=0..5) + em/pad 9-bit
// pack (y=6).  Pure memory-bound, fully coalesced.
// ---------------------------------------------------------------------------
__global__ __launch_bounds__(256) void prep_kernel(
        const float* __restrict__ q,  const float* __restrict__ k,
        const float* __restrict__ wq, const float* __restrict__ wk,
        const float* __restrict__ wv, const float* __restrict__ wh,
        const float* __restrict__ em, const float* __restrict__ pad,
        unsigned short* __restrict__ qb,  unsigned short* __restrict__ kb,
        unsigned short* __restrict__ wqb, unsigned short* __restrict__ wkb,
        unsigned short* __restrict__ wvb, unsigned short* __restrict__ whb,
        unsigned short* __restrict__ Pk) {
    const int tid = threadIdx.x;
    const int y = blockIdx.y;
    if (y < 6) {
        const float* s; unsigned short* d; int n;
        switch (y) {
            case 0: s = q;  d = qb;  n = NB * LQ * DM; break;
            case 1: s = k;  d = kb;  n = NB * LK * DM; break;
            case 2: s = wq; d = wqb; n = DM * DM; break;
            case 3: s = wk; d = wkb; n = DM * DM; break;
            case 4: s = wv; d = wvb; n = DM * DM; break;
            default: s = wh; d = whb; n = DM * DM; break;
        }
        const int i = blockIdx.x * 256 + tid;
        if (i * 8 >= n) return;
        const float4* sv = (const float4*)s;
        const float4 a = sv[2 * (size_t)i], b = sv[2 * (size_t)i + 1];
        uint4 o;
        o.x = (unsigned)f2bf(a.x) | ((unsigned)f2bf(a.y) << 16);
        o.y = (unsigned)f2bf(a.z) | ((unsigned)f2bf(a.w) << 16);
        o.z = (unsigned)f2bf(b.x) | ((unsigned)f2bf(b.y) << 16);
        o.w = (unsigned)f2bf(b.z) | ((unsigned)f2bf(b.w) << 16);
        *(uint4*)(d + (size_t)i * 8) = o;
    } else {
        if (blockIdx.x >= 512) return;
        const int row = blockIdx.x * 4 + (tid >> 6);      // bq row
        const int k0 = (tid & 63) * 8;
        const float* eb = em + ((size_t)row * LK + k0) * NL;
        const float4 pv0 = *(const float4*)(pad + (size_t)row * LK + k0);
        const float4 pv1 = *(const float4*)(pad + (size_t)row * LK + k0 + 4);
        const float pv[8] = {pv0.x, pv0.y, pv0.z, pv0.w, pv1.x, pv1.y, pv1.z, pv1.w};
        unsigned short outv[8];
#pragma unroll
        for (int kk = 0; kk < 8; ++kk) {
            const float4 v0 = *(const float4*)(eb + kk * 8);
            const float4 v1 = *(const float4*)(eb + kk * 8 + 4);
            unsigned b_ = 0;
            b_ |= (v0.x != 0.f) << 0; b_ |= (v0.y != 0.f) << 1;
            b_ |= (v0.z != 0.f) << 2; b_ |= (v0.w != 0.f) << 3;
            b_ |= (v1.x != 0.f) << 4; b_ |= (v1.y != 0.f) << 5;
            b_ |= (v1.z != 0.f) << 6; b_ |= (v1.w != 0.f) << 7;
            b_ |= (pv[kk] != 0.f) << 8;
            outv[kk] = (unsigned short)b_;
        }
        uint4 o;
        o.x = (unsigned)outv[0] | ((unsigned)outv[1] << 16);
        o.y = (unsigned)outv[2] | ((unsigned)outv[3] << 16);
        o.z = (unsigned)outv[4] | ((unsigned)outv[5] << 16);
        o.w = (unsigned)outv[6] | ((unsigned)outv[7] << 16);
        *(uint4*)(Pk + (size_t)row * LK + k0) = o;
    }
}

// ---------------------------------------------------------------------------
// Barrier-free GEMM core: fragments loaded DIRECTLY from global (L2-resident).
// C(64x64) += A(64xK)*B(64xK)^T.  256 thr = 4 waves (2x2), no LDS at all.
// ---------------------------------------------------------------------------
__device__ __forceinline__ void gemm64_direct(const unsigned short* __restrict__ Ag, int lda,
                                              const unsigned short* __restrict__ Bg, int ldb,
                                              int K, f32x4 (&acc)[2][2]) {
    const int tid = threadIdx.x;
    const int wave = tid >> 6, lane = tid & 63;
    const int quad = lane >> 4, l16 = lane & 15;
    const int wr = wave >> 1, wc = wave & 1;
    const unsigned short* a0 = Ag + (size_t)(wr * 32 + l16) * lda + quad * 8;
    const unsigned short* a1 = a0 + 16 * lda;
    const unsigned short* b0 = Bg + (size_t)(wc * 32 + l16) * ldb + quad * 8;
    const unsigned short* b1 = b0 + 16 * ldb;
    for (int k0 = 0; k0 < K; k0 += 32) {
        bf16x8 af[2], bf[2];
        af[0] = *(const bf16x8*)(a0 + k0);
        af[1] = *(const bf16x8*)(a1 + k0);
        bf[0] = *(const bf16x8*)(b0 + k0);
        bf[1] = *(const bf16x8*)(b1 + k0);
#pragma unroll
        for (int i = 0; i < 2; ++i)
#pragma unroll
            for (int j = 0; j < 2; ++j)
                acc[i][j] = __builtin_amdgcn_mfma_f32_16x16x32_bf16(af[i], bf[j], acc[i][j], 0, 0, 0);
    }
}

// ---------------------------------------------------------------------------
// Input projections, barrier-free.  z: 0=Q, 1=K, 2=V-transposed.
// ---------------------------------------------------------------------------
__global__ __launch_bounds__(256) void proj_all(const unsigned short* __restrict__ qb,
                                                const unsigned short* __restrict__ kb,
                                                const unsigned short* __restrict__ wqb,
                                                const unsigned short* __restrict__ wkb,
                                                const unsigned short* __restrict__ wvb,
                                                const float* __restrict__ w_q_b,
                                                unsigned short* __restrict__ Qp,
                                                unsigned short* __restrict__ Kp,
                                                unsigned short* __restrict__ Vt) {
    const unsigned short* A; const unsigned short* W; const float* bias;
    unsigned short* C; int mode;
    switch (blockIdx.z) {
        case 0:  A = qb; W = wqb; bias = w_q_b;  C = Qp; mode = 0; break;
        case 1:  A = kb; W = wkb; bias = nullptr; C = Kp; mode = 0; break;
        default: A = kb; W = wvb; bias = nullptr; C = Vt; mode = 1; break;
    }
    f32x4 acc[2][2];
    const f32x4 zz = {0.f, 0.f, 0.f, 0.f};
#pragma unroll
    for (int i = 0; i < 2; ++i)
#pragma unroll
        for (int j = 0; j < 2; ++j) acc[i][j] = zz;
    const int m0 = blockIdx.x * 64, n0 = blockIdx.y * 64;
    gemm64_direct(A + (size_t)m0 * DM, DM, W + (size_t)n0 * DM, DM, DM, acc);
    const int tid = threadIdx.x, wave = tid >> 6, lane = tid & 63;
    const int quad = lane >> 4, l16 = lane & 15;
    const int wr = wave >> 1, wc = wave & 1;
#pragma unroll
    for (int i = 0; i < 2; ++i)
#pragma unroll
        for (int r = 0; r < 4; ++r) {
            const int gm = m0 + wr * 32 + i * 16 + quad * 4 + r;
#pragma unroll
            for (int j = 0; j < 2; ++j) {
                const int gn = n0 + wc * 32 + j * 16 + l16;
                float v = acc[i][j][r];
                if (bias) v += bias[gn];
                if (mode == 0) C[(size_t)gm * DM + gn] = f2bf(v);
                else C[(size_t)(gm >> 9) * (DM * LK) + (size_t)gn * LK + (gm & 511)] = f2bf(v);
            }
        }
}

// ---------------------------------------------------------------------------
// Fused attention per (z = h*4+b, 32-q-row tile).  512 thr = 8 waves.
// Q/K/V MFMA fragments loaded DIRECTLY from global (all L2-resident) -> the
// QK and PV phases have NO staging barriers.  Only the P transpose (C-layout
// -> A-layout) round-trips through LDS.  4 barriers total per block.
// ---------------------------------------------------------------------------
__global__ __launch_bounds__(512, 4) void attn_fused(
        const unsigned short* __restrict__ Qp,
        const unsigned short* __restrict__ Kp,
        const unsigned short* __restrict__ Vt,
        const unsigned short* __restrict__ Pk,
        const float* __restrict__ b_ks,
        const float* __restrict__ b_vs,
        float* __restrict__ weights,
        unsigned short* __restrict__ Hb) {
    __shared__ __align__(16) short Ps[QT * PSTR];     // 32.5 KB attn bf16
    __shared__ float svS[QT * NL];
    __shared__ float tS[QT * NL];
    __shared__ float redA[QT * 8];                    // per-wave-group max
    __shared__ float redB[QT * 8];                    // per-wave-group sum

    const int tid = threadIdx.x, wave = tid >> 6, lane = tid & 63;
    const int quad = lane >> 4, l16 = lane & 15;
    const int q0 = blockIdx.x * QT;
    const int z = blockIdx.y, h = z >> 2, b = z & 3;

    // ---- A-fragments for QK (loaded once; d = kd2*32 + quad*8 + j) ----
    bf16x8 af[2][2];
#pragma unroll
    for (int kd2 = 0; kd2 < 2; ++kd2)
#pragma unroll
        for (int i = 0; i < 2; ++i)
            af[kd2][i] = *(const bf16x8*)(Qp + (size_t)(b * LQ + q0 + i * 16 + l16) * DM
                                          + h * DQ + kd2 * 32 + quad * 8);

    // ---- sv[row][l] = sum_d Q[row][d]*b_ks[l][d] (tid<256; L1-served) ----
    if (tid < 256) {
        const int row = tid >> 3, l = tid & 7;
        const unsigned short* qrow = Qp + (size_t)(b * LQ + q0 + row) * DM + h * DQ;
        const float* bk = b_ks + l * DQ;
        float s = 0.f;
#pragma unroll
        for (int d = 0; d < DQ; ++d) s = fmaf(bf2f(qrow[d]), bk[d], s);
        svS[row * 8 + l] = s;
    }

    // ---- QK^T: S[32 x 512], wave owns cols c*128 + wave*16 + [0,16) ----
    f32x4 acc[4][2];
    const f32x4 zz = {0.f, 0.f, 0.f, 0.f};
#pragma unroll
    for (int c = 0; c < 4; ++c) { acc[c][0] = zz; acc[c][1] = zz; }
#pragma unroll
    for (int c = 0; c < 4; ++c) {
        const unsigned short* kbase = Kp + (size_t)(b * LK + c * 128 + wave * 16 + l16) * DM
                                      + h * DQ + quad * 8;
#pragma unroll
        for (int kd2 = 0; kd2 < 2; ++kd2) {
            const bf16x8 bfv = *(const bf16x8*)(kbase + kd2 * 32);
            acc[c][0] = __builtin_amdgcn_mfma_f32_16x16x32_bf16(af[kd2][0], bfv, acc[c][0], 0, 0, 0);
            acc[c][1] = __builtin_amdgcn_mfma_f32_16x16x32_bf16(af[kd2][1], bfv, acc[c][1], 0, 0, 0);
        }
    }
    __syncthreads();   // svS visible

    // ---- pass A: rel + mask + weights write + per-wave-group (max,sum) ----
#pragma unroll
    for (int i = 0; i < 2; ++i)
#pragma unroll
        for (int r = 0; r < 4; ++r) {
            const int row = i * 16 + quad * 4 + r;
            const int gq = q0 + row;
            const f32x4 sv0 = *(const f32x4*)&svS[row * 8];
            const f32x4 sv1 = *(const f32x4*)&svS[row * 8 + 4];
            const unsigned short* prow = Pk + (size_t)(b * LQ + gq) * LK;
            float* wrow = weights + ((size_t)z * LQ + gq) * LK;
            float pm = -__builtin_inff();
#pragma unroll
            for (int c = 0; c < 4; ++c) {
                const int col = c * 128 + wave * 16 + l16;
                const unsigned w_ = prow[col];
                float rel = 0.f;
                rel = fmaf((float)((w_ >> 0) & 1), sv0[0], rel);
                rel = fmaf((float)((w_ >> 1) & 1), sv0[1], rel);
                rel = fmaf((float)((w_ >> 2) & 1), sv0[2], rel);
                rel = fmaf((float)((w_ >> 3) & 1), sv0[3], rel);
                rel = fmaf((float)((w_ >> 4) & 1), sv1[0], rel);
                rel = fmaf((float)((w_ >> 5) & 1), sv1[1], rel);
                rel = fmaf((float)((w_ >> 6) & 1), sv1[2], rel);
                rel = fmaf((float)((w_ >> 7) & 1), sv1[3], rel);
                const float wv = (acc[c][i][r] + rel) * 0.125f;
                wrow[col] = wv;                               // pre-mask weights
                const float m = ((w_ & 0x1FFu) == 0x100u) ? -__builtin_inff() : wv;
                acc[c][i][r] = m;
                pm = fmaxf(pm, m);
            }
#pragma unroll
            for (int o = 1; o < 16; o <<= 1) pm = fmaxf(pm, __shfl_xor(pm, o, 64));
            float ps = 0.f;
#pragma unroll
            for (int c = 0; c < 4; ++c) {
                const float e = __expf(acc[c][i][r] - pm);    // masked -> 0
                acc[c][i][r] = e;
                ps += e;
            }
#pragma unroll
            for (int o = 1; o < 16; o <<= 1) ps += __shfl_xor(ps, o, 64);
            if (l16 == 0) { redA[row * 8 + wave] = pm; redB[row * 8 + wave] = ps; }
        }
    __syncthreads();

    // ---- pass B: merge 8 wave-group partials, normalize, write Ps ----
#pragma unroll
    for (int i = 0; i < 2; ++i)
#pragma unroll
        for (int r = 0; r < 4; ++r) {
            const int row = i * 16 + quad * 4 + r;
            const f32x4 pa = *(const f32x4*)&redA[row * 8];
            const f32x4 pb = *(const f32x4*)&redA[row * 8 + 4];
            const f32x4 sa = *(const f32x4*)&redB[row * 8];
            const f32x4 sb = *(const f32x4*)&redB[row * 8 + 4];
            const float M = fmaxf(fmaxf(fmaxf(pa[0], pa[1]), fmaxf(pa[2], pa[3])),
                                  fmaxf(fmaxf(pb[0], pb[1]), fmaxf(pb[2], pb[3])));
            const float S = sa[0] * __expf(pa[0] - M) + sa[1] * __expf(pa[1] - M)
                          + sa[2] * __expf(pa[2] - M) + sa[3] * __expf(pa[3] - M)
                          + sb[0] * __expf(pb[0] - M) + sb[1] * __expf(pb[1] - M)
                          + sb[2] * __expf(pb[2] - M) + sb[3] * __expf(pb[3] - M);
            const float own = redA[row * 8 + wave];
            const float alpha = __expf(own - M) / S;
#pragma unroll
            for (int c = 0; c < 4; ++c) {
                const int col = c * 128 + wave * 16 + l16;
                Ps[row * PSTR + col] = (short)f2bf(acc[c][i][r] * alpha);
            }
        }
    __syncthreads();   // Ps visible

    // ---- t[q][l] = sum_k attn * em_bit_l (b128 LDS reads, broadcast) ----
    {
        const int row = tid >> 4, l = (tid >> 1) & 7, half = tid & 1;
        const uint4* pw = (const uint4*)(Pk + (size_t)(b * LQ + q0 + row) * LK + half * 256);
        const uint4* aw = (const uint4*)&Ps[row * PSTR + half * 256];
        float tv = 0.f;
#pragma unroll 4
        for (int kk = 0; kk < 32; ++kk) {
            const uint4 wb = pw[kk];
            const uint4 av = aw[kk];
            const unsigned w4[4] = {wb.x, wb.y, wb.z, wb.w};
            const unsigned a4[4] = {av.x, av.y, av.z, av.w};
#pragma unroll
            for (int u = 0; u < 4; ++u) {
                tv += ((w4[u] >> l) & 1)        ? bf2f(a4[u] & 0xffffu) : 0.f;
                tv += ((w4[u] >> (16 + l)) & 1) ? bf2f(a4[u] >> 16)     : 0.f;
            }
        }
        tv += __shfl_xor(tv, 1, 64);
        if (half == 0) tS[row * 8 + l] = tv;
    }

    // ---- PV: O[32 x 64] = attn @ V, V fragments direct from global ----
    f32x4 oacc = zz;
    const int mi = wave & 1, ni = wave >> 1;
    const unsigned short* vbase = Vt + (size_t)(b * DM + h * DQ + ni * 16 + l16) * LK + quad * 8;
    const short* pbase = &Ps[(mi * 16 + l16) * PSTR + quad * 8];
#pragma unroll
    for (int kk = 0; kk < LK; kk += 32) {
        const bf16x8 afv = *(const bf16x8*)(pbase + kk);
        const bf16x8 bfv = *(const bf16x8*)(vbase + kk);
        oacc = __builtin_amdgcn_mfma_f32_16x16x32_bf16(afv, bfv, oacc, 0, 0, 0);
    }

    __syncthreads();   // tS written by t-loop threads must be visible to all
                       // (round-8 bug: missing this barrier -> race on tS)

    // ---- output epilogue: + qvr, store Hb bf16 ----
    const int gd = ni * 16 + l16;
    float bvv[NL];
#pragma unroll
    for (int l = 0; l < NL; ++l) bvv[l] = b_vs[l * DQ + gd];
#pragma unroll
    for (int r = 0; r < 4; ++r) {
        const int row = mi * 16 + quad * 4 + r;
        const float* tp = &tS[row * 8];
        float o = oacc[r];
#pragma unroll
        for (int l = 0; l < NL; ++l) o = fmaf(tp[l], bvv[l], o);
        Hb[(size_t)(b * LQ + q0 + row) * DM + h * DQ + gd] = f2bf(o);
    }
}

// ---------------------------------------------------------------------------
// Output projection: Hb(bf16) @ whb(bf16)^T + bias, fp32 store, barrier-free.
// ---------------------------------------------------------------------------
__global__ __launch_bounds__(256) void outproj_mfma(const unsigned short* __restrict__ Hb,
                                                    const unsigned short* __restrict__ whb,
                                                    const float* __restrict__ bias,
                                                    float* __restrict__ C) {
    f32x4 acc[2][2];
    const f32x4 zz = {0.f, 0.f, 0.f, 0.f};
#pragma unroll
    for (int i = 0; i < 2; ++i)
#pragma unroll
        for (int j = 0; j < 2; ++j) acc[i][j] = zz;
    const int m0 = blockIdx.x * 64, n0 = blockIdx.y * 64;
    gemm64_direct(Hb + (size_t)m0 * DM, DM, whb + (size_t)n0 * DM, DM, DM, acc);
    const int tid = threadIdx.x, wave = tid >> 6, lane = tid & 63;
    const int quad = lane >> 4, l16 = lane & 15;
    const int wr = wave >> 1, wc = wave & 1;
#pragma unroll
    for (int i = 0; i < 2; ++i)
#pragma unroll
        for (int r = 0; r < 4; ++r) {
            const int gm = m0 + wr * 32 + i * 16 + quad * 4 + r;
#pragma unroll
            for (int j = 0; j < 2; ++j) {
                const int gn = n0 + wc * 32 + j * 16 + l16;
                C[(size_t)gm * DM + gn] = acc[i][j][r] + bias[gn];
            }
        }
}

// ---------------------------------------------------------------------------
extern "C" void kernel_launch(void* const* d_in, const int* in_sizes, int n_in,
                              void* d_out, int out_size, void* d_ws, size_t ws_size,
                              hipStream_t stream) {
    const float* q     = (const float*)d_in[0];
    const float* k     = (const float*)d_in[1];
    const float* em    = (const float*)d_in[2];
    const float* pad   = (const float*)d_in[3];
    const float* w_q_w = (const float*)d_in[4];
    const float* w_q_b = (const float*)d_in[5];
    const float* w_k   = (const float*)d_in[6];
    const float* w_v   = (const float*)d_in[7];
    const float* w_h_w = (const float*)d_in[8];
    const float* w_h_b = (const float*)d_in[9];
    const float* b_ks  = (const float*)d_in[10];
    const float* b_vs  = (const float*)d_in[11];

    float* out     = (float*)d_out;                       // (B, LQ, DM) fp32
    float* weights = out + (size_t)NB * LQ * DM;          // (H*B, LQ, LK) fp32

    char* ws = (char*)d_ws;
    unsigned short* qb  = (unsigned short*)(ws + 0);          // 2 MB
    unsigned short* kb  = (unsigned short*)(ws + 2097152);    // 2 MB
    unsigned short* wqb = (unsigned short*)(ws + 4194304);    // 512 KB
    unsigned short* wkb = (unsigned short*)(ws + 4718592);
    unsigned short* wvb = (unsigned short*)(ws + 5242880);
    unsigned short* whb = (unsigned short*)(ws + 5767168);
    unsigned short* Qp  = (unsigned short*)(ws + 6291456);    // 2 MB
    unsigned short* Kp  = (unsigned short*)(ws + 8388608);    // 2 MB
    unsigned short* Vt  = (unsigned short*)(ws + 10485760);   // 2 MB
    unsigned short* Hb  = (unsigned short*)(ws + 12582912);   // 2 MB
    unsigned short* Pk  = (unsigned short*)(ws + 14680064);   // 2 MB

    prep_kernel<<<dim3(1024, 7), 256, 0, stream>>>(q, k, w_q_w, w_k, w_v, w_h_w,
                                                   em, pad, qb, kb, wqb, wkb, wvb, whb, Pk);
    proj_all<<<dim3(32, 8, 3), 256, 0, stream>>>(qb, kb, wqb, wkb, wvb, w_q_b, Qp, Kp, Vt);
    attn_fused<<<dim3(LQ / QT, 32), 512, 0, stream>>>(Qp, Kp, Vt, Pk, b_ks, b_vs, weights, Hb);
    outproj_mfma<<<dim3(32, 8), 256, 0, stream>>>(Hb, whb, w_h_b, out);
}